// Round 1
// baseline (1524.416 us; speedup 1.0000x reference)
//
#include <hip/hip_runtime.h>
#include <math.h>

#define L_SEQ 2048
#define NB 4
#define DM 512
#define DI 1024
#define DS 16
#define DTR 32
#define MROWS (NB * L_SEQ)  // 8192

__device__ __forceinline__ float siluf(float x) { return x / (1.f + __expf(-x)); }
__device__ __forceinline__ float softplusf(float x) { return x > 20.f ? x : log1pf(expf(x)); }

// ---------------- LayerNorm + residual copy ----------------
__global__ __launch_bounds__(256)
void ln_kernel(const float* __restrict__ hs, const float* __restrict__ nw,
               const float* __restrict__ nb, float* __restrict__ h,
               float* __restrict__ resid)
{
    int r = blockIdx.x;
    int tid = threadIdx.x;
    const float2* rp = (const float2*)(hs + (size_t)r * DM);
    float2 v = rp[tid];
    float s1 = v.x + v.y;
    float s2 = v.x * v.x + v.y * v.y;
#pragma unroll
    for (int off = 32; off >= 1; off >>= 1) {
        s1 += __shfl_down(s1, off);
        s2 += __shfl_down(s2, off);
    }
    __shared__ float r1[4], r2[4];
    int wid = tid >> 6, lane = tid & 63;
    if (lane == 0) { r1[wid] = s1; r2[wid] = s2; }
    __syncthreads();
    s1 = r1[0] + r1[1] + r1[2] + r1[3];
    s2 = r2[0] + r2[1] + r2[2] + r2[3];
    float mean = s1 * (1.f / DM);
    float var = s2 * (1.f / DM) - mean * mean;
    float rstd = rsqrtf(var + 1e-5f);
    float2 w = ((const float2*)nw)[tid];
    float2 bb = ((const float2*)nb)[tid];
    float2 o;
    o.x = (v.x - mean) * rstd * w.x + bb.x;
    o.y = (v.y - mean) * rstd * w.y + bb.y;
    ((float2*)(h + (size_t)r * DM))[tid] = o;
    ((float2*)(resid + (size_t)r * DM))[tid] = v;
}

// ---------------- Generic fp32 NT GEMM: C[m,n] = scale * sum_k A[m,k]*B[n,k] ----------------
// Tile 64x64, BK=16, 256 threads, 4x4 per thread. M,N multiples of 64; K multiple of 16.
// DUAL: A := A + A2 (elementwise).  SP: epilogue softplus(v + bias[n_global]).
template <int DUAL, int SP>
__global__ __launch_bounds__(256)
void gemm_nt(const float* __restrict__ A, int lda,
             const float* __restrict__ A2, int lda2,
             const float* __restrict__ B, int ldb,
             const float* __restrict__ bias,
             float* __restrict__ C, int ldc,
             int K, float scale)
{
    __shared__ float sA[16][64];
    __shared__ float sB[16][64];
    const int tid = threadIdx.x;
    const size_t bm = (size_t)blockIdx.y * 64;
    const size_t bn = (size_t)blockIdx.x * 64;
    const int lr = tid >> 2;         // 0..63
    const int lc = (tid & 3) << 2;   // 0,4,8,12
    const int tx = tid & 15;
    const int ty = tid >> 4;
    float acc[4][4];
#pragma unroll
    for (int i = 0; i < 4; i++)
#pragma unroll
        for (int j = 0; j < 4; j++) acc[i][j] = 0.f;

    const float* aptr = A + (bm + lr) * (size_t)lda + lc;
    const float* bptr = B + (bn + lr) * (size_t)ldb + lc;
    const float* a2ptr = DUAL ? (A2 + (bm + lr) * (size_t)lda2 + lc) : nullptr;

    for (int k0 = 0; k0 < K; k0 += 16) {
        float4 av = *(const float4*)(aptr + k0);
        if (DUAL) {
            float4 a2 = *(const float4*)(a2ptr + k0);
            av.x += a2.x; av.y += a2.y; av.z += a2.z; av.w += a2.w;
        }
        float4 bv = *(const float4*)(bptr + k0);
        sA[lc + 0][lr] = av.x; sA[lc + 1][lr] = av.y; sA[lc + 2][lr] = av.z; sA[lc + 3][lr] = av.w;
        sB[lc + 0][lr] = bv.x; sB[lc + 1][lr] = bv.y; sB[lc + 2][lr] = bv.z; sB[lc + 3][lr] = bv.w;
        __syncthreads();
#pragma unroll
        for (int kk = 0; kk < 16; kk++) {
            float4 a = *(const float4*)&sA[kk][ty << 2];
            float4 b = *(const float4*)&sB[kk][tx << 2];
            acc[0][0] += a.x * b.x; acc[0][1] += a.x * b.y; acc[0][2] += a.x * b.z; acc[0][3] += a.x * b.w;
            acc[1][0] += a.y * b.x; acc[1][1] += a.y * b.y; acc[1][2] += a.y * b.z; acc[1][3] += a.y * b.w;
            acc[2][0] += a.z * b.x; acc[2][1] += a.z * b.y; acc[2][2] += a.z * b.z; acc[2][3] += a.z * b.w;
            acc[3][0] += a.w * b.x; acc[3][1] += a.w * b.y; acc[3][2] += a.w * b.z; acc[3][3] += a.w * b.w;
        }
        __syncthreads();
    }
#pragma unroll
    for (int i = 0; i < 4; i++) {
        size_t m = bm + (ty << 2) + i;
#pragma unroll
        for (int j = 0; j < 4; j++) {
            size_t n = bn + (tx << 2) + j;
            float v = acc[i][j] * scale;
            if (SP) v = softplusf(v + bias[n]);
            C[m * (size_t)ldc + n] = v;
        }
    }
}

// ---------------- Depthwise causal (fwd) + anti-causal (bwd) conv + SiLU ----------------
// xc_f[b,l,d] = silu( sum_k x[b,l-3+k,d]*cwf[d,k] + cbf[d] )
// xc_b[b,l,d] = silu( sum_j x[b,l+j,d]*cwb[d,3-j] + cbb[d] )   (reverse-conv-reverse identity)
__global__ __launch_bounds__(256)
void conv_kernel(const float* __restrict__ xz,
                 const float* __restrict__ cwf, const float* __restrict__ cbf,
                 const float* __restrict__ cwb, const float* __restrict__ cbb,
                 float* __restrict__ xcf, float* __restrict__ xcb)
{
    int r = blockIdx.x;           // 0..8191
    int b = r >> 11, l = r & (L_SEQ - 1);
    int tid = threadIdx.x;
#pragma unroll
    for (int i = 0; i < 4; i++) {
        int d = tid + (i << 8);
        float accf = cbf[d], accb = cbb[d];
#pragma unroll
        for (int k = 0; k < 4; k++) {
            int lf = l - 3 + k;
            if (lf >= 0)
                accf += xz[((size_t)(b * L_SEQ + lf)) * (2 * DI) + d] * cwf[(d << 2) + k];
            int lb = l + k;
            if (lb < L_SEQ)
                accb += xz[((size_t)(b * L_SEQ + lb)) * (2 * DI) + d] * cwb[(d << 2) + 3 - k];
        }
        xcf[(size_t)r * DI + d] = siluf(accf);
        xcb[(size_t)r * DI + d] = siluf(accb);
    }
}

// ---------------- Selective scan (both directions in one launch) ----------------
// 16 lanes per channel, one state per lane; h in register; butterfly reduce for y.
__global__ __launch_bounds__(256)
void scan_kernel(const float* __restrict__ xz,
                 const float* __restrict__ xcf, const float* __restrict__ xcb,
                 const float* __restrict__ dtf, const float* __restrict__ dtb,
                 const float* __restrict__ xdbl,
                 const float* __restrict__ alf, const float* __restrict__ alb,
                 const float* __restrict__ dsf, const float* __restrict__ dsb,
                 float* __restrict__ yf, float* __restrict__ yb)
{
    int bid = blockIdx.x;          // 0..511
    int branch = bid >> 8;         // 0 fwd, 1 bwd
    int rem = bid & 255;
    int b = rem >> 6;              // 0..3
    int chunk = rem & 63;          // 0..63
    int tid = threadIdx.x;
    int s = tid & 15;
    int d = chunk * 16 + (tid >> 4);

    const float* xc_buf = branch ? xcb : xcf;
    const float* dt_buf = branch ? dtb : dtf;
    const float* Alog   = branch ? alb : alf;
    const float* Dp     = branch ? dsb : dsf;
    float* yst = branch ? yb : yf;
    const int yld = branch ? DI : 2 * DI;   // yf lives in the x-half of xz (stride 2048)
    const int boff = branch * 64;

    float a = -expf(Alog[d * DS + s]);
    float Dv = Dp[d];
    float h = 0.f;
    const size_t rowbase = (size_t)b * L_SEQ;
    const int l0 = branch ? (L_SEQ - 1) : 0;
    const int dl = branch ? -1 : 1;

    size_t r = rowbase + l0;
    float dt  = dt_buf[r * DI + d];
    float xcv = xc_buf[r * DI + d];
    float Bv  = xdbl[r * 128 + boff + 32 + s];
    float Cv  = xdbl[r * 128 + boff + 48 + s];
    float zv  = xz[r * (2 * DI) + DI + d];

    for (int i = 0; i < L_SEQ; ++i) {
        float dt2 = 0.f, xcv2 = 0.f, Bv2 = 0.f, Cv2 = 0.f, zv2 = 0.f;
        if (i < L_SEQ - 1) {
            size_t r2 = rowbase + l0 + (i + 1) * dl;
            dt2  = dt_buf[r2 * DI + d];
            xcv2 = xc_buf[r2 * DI + d];
            Bv2  = xdbl[r2 * 128 + boff + 32 + s];
            Cv2  = xdbl[r2 * 128 + boff + 48 + s];
            zv2  = xz[r2 * (2 * DI) + DI + d];
        }
        float dA = __expf(dt * a);
        h = dA * h + (dt * xcv) * Bv;
        float p = h * Cv;
        p += __shfl_xor(p, 1);
        p += __shfl_xor(p, 2);
        p += __shfl_xor(p, 4);
        p += __shfl_xor(p, 8);
        if (s == 0) {
            size_t rc = rowbase + l0 + i * dl;
            yst[rc * (size_t)yld + d] = (p + xcv * Dv) * siluf(zv);
        }
        dt = dt2; xcv = xcv2; Bv = Bv2; Cv = Cv2; zv = zv2;
    }
}

extern "C" void kernel_launch(void* const* d_in, const int* in_sizes, int n_in,
                              void* d_out, int out_size, void* d_ws, size_t ws_size,
                              hipStream_t stream)
{
    const float* hs   = (const float*)d_in[0];
    const float* nw   = (const float*)d_in[1];
    const float* nbp  = (const float*)d_in[2];
    const float* ipw  = (const float*)d_in[3];
    const float* opw  = (const float*)d_in[4];
    const float* cwf  = (const float*)d_in[5];
    const float* cbf  = (const float*)d_in[6];
    const float* xpwf = (const float*)d_in[7];
    const float* dtwf = (const float*)d_in[8];
    const float* dtbf = (const float*)d_in[9];
    const float* alf  = (const float*)d_in[10];
    const float* dsf  = (const float*)d_in[11];
    const float* cwb  = (const float*)d_in[12];
    const float* cbb  = (const float*)d_in[13];
    const float* xpwb = (const float*)d_in[14];
    const float* dtwb = (const float*)d_in[15];
    const float* dtbb = (const float*)d_in[16];
    const float* alb  = (const float*)d_in[17];
    const float* dsb  = (const float*)d_in[18];

    float* out   = (float*)d_out;                       // [8192][512]
    float* resid = out + (size_t)MROWS * DM;            // [8192][512]

    // ws layout (fp32), ~244 MiB total
    float* ws = (float*)d_ws;
    float* h    = ws;  ws += (size_t)MROWS * DM;        // 8192x512
    float* xz   = ws;  ws += (size_t)MROWS * 2 * DI;    // 8192x2048 (x | z); x-half becomes y_f
    float* xcf  = ws;  ws += (size_t)MROWS * DI;
    float* xcb  = ws;  ws += (size_t)MROWS * DI;
    float* dtfb = ws;  ws += (size_t)MROWS * DI;
    float* dtbb_ = ws; ws += (size_t)MROWS * DI;
    float* xdbl = ws;  ws += (size_t)MROWS * 128;       // [fwd 64 | bwd 64]; cols 32:48=B, 48:64=C
    float* yb   = ws;  ws += (size_t)MROWS * DI;
    float* yf   = xz;                                   // stride 2048, cols 0..1023

    ln_kernel<<<MROWS, 256, 0, stream>>>(hs, nw, nbp, h, resid);

    // xz = h @ in_proj_w^T   (M=8192, N=2048, K=512)
    gemm_nt<0, 0><<<dim3(2 * DI / 64, MROWS / 64), 256, 0, stream>>>(
        h, DM, nullptr, 0, ipw, DM, nullptr, xz, 2 * DI, DM, 1.f);

    conv_kernel<<<MROWS, 256, 0, stream>>>(xz, cwf, cbf, cwb, cbb, xcf, xcb);

    // x_dbl = xc @ x_proj_w^T  (N=64, K=1024), per branch
    gemm_nt<0, 0><<<dim3(1, MROWS / 64), 256, 0, stream>>>(
        xcf, DI, nullptr, 0, xpwf, DI, nullptr, xdbl, 128, DI, 1.f);
    gemm_nt<0, 0><<<dim3(1, MROWS / 64), 256, 0, stream>>>(
        xcb, DI, nullptr, 0, xpwb, DI, nullptr, xdbl + 64, 128, DI, 1.f);

    // dt = softplus(x_dbl[:, :32] @ dt_proj_w^T + b)  (N=1024, K=32), per branch
    gemm_nt<0, 1><<<dim3(DI / 64, MROWS / 64), 256, 0, stream>>>(
        xdbl, 128, nullptr, 0, dtwf, DTR, dtbf, dtfb, DI, DTR, 1.f);
    gemm_nt<0, 1><<<dim3(DI / 64, MROWS / 64), 256, 0, stream>>>(
        xdbl + 64, 128, nullptr, 0, dtwb, DTR, dtbb, dtbb_, DI, DTR, 1.f);

    // selective scan, both directions
    scan_kernel<<<512, 256, 0, stream>>>(xz, xcf, xcb, dtfb, dtbb_, xdbl,
                                         alf, alb, dsf, dsb, yf, yb);

    // out = (y_f + y_b) @ out_proj_w^T * 0.5  (N=512, K=1024)
    gemm_nt<1, 0><<<dim3(DM / 64, MROWS / 64), 256, 0, stream>>>(
        yf, 2 * DI, yb, DI, opw, DI, nullptr, out, DM, DI, 0.5f);
}

// Round 2
// 893.385 us; speedup vs baseline: 1.7063x; 1.7063x over previous
//
#include <hip/hip_runtime.h>
#include <math.h>

#define L_SEQ 2048
#define NB 4
#define DM 512
#define DI 1024
#define DS 16
#define DTR 32
#define MROWS (NB * L_SEQ)  // 8192
#define LC 64               // chunk length
#define NCH 32              // chunks per sequence

__device__ __forceinline__ float siluf(float x) { return x / (1.f + __expf(-x)); }
__device__ __forceinline__ float softplusf(float x) { return x > 20.f ? x : log1pf(expf(x)); }

// ---------------- LayerNorm + residual copy ----------------
__global__ __launch_bounds__(256)
void ln_kernel(const float* __restrict__ hs, const float* __restrict__ nw,
               const float* __restrict__ nb, float* __restrict__ h,
               float* __restrict__ resid)
{
    int r = blockIdx.x;
    int tid = threadIdx.x;
    const float2* rp = (const float2*)(hs + (size_t)r * DM);
    float2 v = rp[tid];
    float s1 = v.x + v.y;
    float s2 = v.x * v.x + v.y * v.y;
#pragma unroll
    for (int off = 32; off >= 1; off >>= 1) {
        s1 += __shfl_down(s1, off);
        s2 += __shfl_down(s2, off);
    }
    __shared__ float r1[4], r2[4];
    int wid = tid >> 6, lane = tid & 63;
    if (lane == 0) { r1[wid] = s1; r2[wid] = s2; }
    __syncthreads();
    s1 = r1[0] + r1[1] + r1[2] + r1[3];
    s2 = r2[0] + r2[1] + r2[2] + r2[3];
    float mean = s1 * (1.f / DM);
    float var = s2 * (1.f / DM) - mean * mean;
    float rstd = rsqrtf(var + 1e-5f);
    float2 w = ((const float2*)nw)[tid];
    float2 bb = ((const float2*)nb)[tid];
    float2 o;
    o.x = (v.x - mean) * rstd * w.x + bb.x;
    o.y = (v.y - mean) * rstd * w.y + bb.y;
    ((float2*)(h + (size_t)r * DM))[tid] = o;
    ((float2*)(resid + (size_t)r * DM))[tid] = v;
}

// ---------------- Generic fp32 NT GEMM: C[m,n] = scale * sum_k A[m,k]*B[n,k] ----------------
template <int DUAL, int SP>
__global__ __launch_bounds__(256)
void gemm_nt(const float* __restrict__ A, int lda,
             const float* __restrict__ A2, int lda2,
             const float* __restrict__ B, int ldb,
             const float* __restrict__ bias,
             float* __restrict__ C, int ldc,
             int K, float scale)
{
    __shared__ float sA[16][64];
    __shared__ float sB[16][64];
    const int tid = threadIdx.x;
    const size_t bm = (size_t)blockIdx.y * 64;
    const size_t bn = (size_t)blockIdx.x * 64;
    const int lr = tid >> 2;         // 0..63
    const int lc = (tid & 3) << 2;   // 0,4,8,12
    const int tx = tid & 15;
    const int ty = tid >> 4;
    float acc[4][4];
#pragma unroll
    for (int i = 0; i < 4; i++)
#pragma unroll
        for (int j = 0; j < 4; j++) acc[i][j] = 0.f;

    const float* aptr = A + (bm + lr) * (size_t)lda + lc;
    const float* bptr = B + (bn + lr) * (size_t)ldb + lc;
    const float* a2ptr = DUAL ? (A2 + (bm + lr) * (size_t)lda2 + lc) : nullptr;

    for (int k0 = 0; k0 < K; k0 += 16) {
        float4 av = *(const float4*)(aptr + k0);
        if (DUAL) {
            float4 a2 = *(const float4*)(a2ptr + k0);
            av.x += a2.x; av.y += a2.y; av.z += a2.z; av.w += a2.w;
        }
        float4 bv = *(const float4*)(bptr + k0);
        sA[lc + 0][lr] = av.x; sA[lc + 1][lr] = av.y; sA[lc + 2][lr] = av.z; sA[lc + 3][lr] = av.w;
        sB[lc + 0][lr] = bv.x; sB[lc + 1][lr] = bv.y; sB[lc + 2][lr] = bv.z; sB[lc + 3][lr] = bv.w;
        __syncthreads();
#pragma unroll
        for (int kk = 0; kk < 16; kk++) {
            float4 a = *(const float4*)&sA[kk][ty << 2];
            float4 b = *(const float4*)&sB[kk][tx << 2];
            acc[0][0] += a.x * b.x; acc[0][1] += a.x * b.y; acc[0][2] += a.x * b.z; acc[0][3] += a.x * b.w;
            acc[1][0] += a.y * b.x; acc[1][1] += a.y * b.y; acc[1][2] += a.y * b.z; acc[1][3] += a.y * b.w;
            acc[2][0] += a.z * b.x; acc[2][1] += a.z * b.y; acc[2][2] += a.z * b.z; acc[2][3] += a.z * b.w;
            acc[3][0] += a.w * b.x; acc[3][1] += a.w * b.y; acc[3][2] += a.w * b.z; acc[3][3] += a.w * b.w;
        }
        __syncthreads();
    }
#pragma unroll
    for (int i = 0; i < 4; i++) {
        size_t m = bm + (ty << 2) + i;
#pragma unroll
        for (int j = 0; j < 4; j++) {
            size_t n = bn + (tx << 2) + j;
            float v = acc[i][j] * scale;
            if (SP) v = softplusf(v + bias[n]);
            C[m * (size_t)ldc + n] = v;
        }
    }
}

// ---------------- Depthwise causal (fwd) + anti-causal (bwd) conv + SiLU ----------------
__global__ __launch_bounds__(256)
void conv_kernel(const float* __restrict__ xz,
                 const float* __restrict__ cwf, const float* __restrict__ cbf,
                 const float* __restrict__ cwb, const float* __restrict__ cbb,
                 float* __restrict__ xcf, float* __restrict__ xcb)
{
    int r = blockIdx.x;           // 0..8191
    int b = r >> 11, l = r & (L_SEQ - 1);
    int tid = threadIdx.x;
#pragma unroll
    for (int i = 0; i < 4; i++) {
        int d = tid + (i << 8);
        float accf = cbf[d], accb = cbb[d];
#pragma unroll
        for (int k = 0; k < 4; k++) {
            int lf = l - 3 + k;
            if (lf >= 0)
                accf += xz[((size_t)(b * L_SEQ + lf)) * (2 * DI) + d] * cwf[(d << 2) + k];
            int lb = l + k;
            if (lb < L_SEQ)
                accb += xz[((size_t)(b * L_SEQ + lb)) * (2 * DI) + d] * cwb[(d << 2) + 3 - k];
        }
        xcf[(size_t)r * DI + d] = siluf(accf);
        xcb[(size_t)r * DI + d] = siluf(accb);
    }
}

// ---------------- Chunked selective scan ----------------
// pass1: per (branch,b,chunk,d): local scan with h0=0 -> q[16] (final local h), Dt = sum(dt).
// Lanes span d -> dt/xc loads coalesced. B-row address is wave-uniform -> scalar loads.
__global__ __launch_bounds__(256)
void scan_pass1(const float* __restrict__ xcf, const float* __restrict__ xcb,
                const float* __restrict__ dtf, const float* __restrict__ dtb,
                const float* __restrict__ xdbl,
                const float* __restrict__ alf, const float* __restrict__ alb,
                float* __restrict__ q_buf, float* __restrict__ dtsum_buf)
{
    const int bid = blockIdx.x;
    const int d  = ((bid & 3) << 8) + threadIdx.x;
    const int c  = (bid >> 2) & 31;
    const int b  = (bid >> 7) & 3;
    const int br = bid >> 9;

    const float* xc_buf = br ? xcb : xcf;
    const float* dt_buf = br ? dtb : dtf;
    const float* Alog   = br ? alb : alf;
    const int boff = br * 64;

    float a[16];
#pragma unroll
    for (int s = 0; s < 16; s++) a[s] = -__expf(Alog[d * DS + s]);

    float h[16];
#pragma unroll
    for (int s = 0; s < 16; s++) h[s] = 0.f;
    float Dt = 0.f;

    const size_t rowbase = (size_t)b * L_SEQ;
    const int lstart = br ? (L_SEQ - 1 - c * LC) : (c * LC);
    const int dl = br ? -1 : 1;

    size_t r0 = rowbase + lstart;
    float dt = dt_buf[r0 * DI + d];
    float xc = xc_buf[r0 * DI + d];

    for (int i = 0; i < LC; i++) {
        size_t r = rowbase + lstart + i * dl;
        float dt_n = 0.f, xc_n = 0.f;
        if (i < LC - 1) {
            size_t rn = rowbase + lstart + (i + 1) * dl;
            dt_n = dt_buf[rn * DI + d];
            xc_n = xc_buf[rn * DI + d];
        }
        const float* brow = xdbl + r * 128 + boff + 32;  // wave-uniform
        float w = dt * xc;
        Dt += dt;
#pragma unroll
        for (int s = 0; s < 16; s++) {
            float e = __expf(dt * a[s]);
            h[s] = e * h[s] + w * brow[s];
        }
        dt = dt_n; xc = xc_n;
    }

    size_t base = ((((size_t)br * 4 + b) * NCH + c) * DI + d);
#pragma unroll
    for (int s = 0; s < 16; s++) q_buf[base * 16 + s] = h[s];
    dtsum_buf[base] = Dt;
}

// pass2: sequential combine over chunk summaries. 16 lanes per channel (lane = s).
// h_start[c] = h at chunk c entry; h_next = exp(a*Dt[c]) * h + q[c].
__global__ __launch_bounds__(256)
void scan_pass2(const float* __restrict__ q_buf, const float* __restrict__ dtsum_buf,
                const float* __restrict__ alf, const float* __restrict__ alb,
                float* __restrict__ h_start)
{
    int idx = blockIdx.x * 16 + (threadIdx.x >> 4);  // channel 0..8191
    int s = threadIdx.x & 15;
    int br = idx >> 12;
    int b  = (idx >> 10) & 3;
    int d  = idx & 1023;
    const float* Alog = br ? alb : alf;
    float a = -__expf(Alog[d * DS + s]);
    float h = 0.f;
    for (int c = 0; c < NCH; c++) {
        size_t base = ((((size_t)br * 4 + b) * NCH + c) * DI + d);
        h_start[base * 16 + s] = h;
        float Dt = dtsum_buf[base];
        float qv = q_buf[base * 16 + s];
        h = __expf(a * Dt) * h + qv;
    }
}

// pass3: replay each chunk from its correct h_start; produce y.
__global__ __launch_bounds__(256)
void scan_pass3(const float* __restrict__ xz,
                const float* __restrict__ xcf, const float* __restrict__ xcb,
                const float* __restrict__ dtf, const float* __restrict__ dtb,
                const float* __restrict__ xdbl,
                const float* __restrict__ alf, const float* __restrict__ alb,
                const float* __restrict__ dsf, const float* __restrict__ dsb,
                const float* __restrict__ h_start,
                float* __restrict__ yf, float* __restrict__ yb)
{
    const int bid = blockIdx.x;
    const int d  = ((bid & 3) << 8) + threadIdx.x;
    const int c  = (bid >> 2) & 31;
    const int b  = (bid >> 7) & 3;
    const int br = bid >> 9;

    const float* xc_buf = br ? xcb : xcf;
    const float* dt_buf = br ? dtb : dtf;
    const float* Alog   = br ? alb : alf;
    const float* Dp     = br ? dsb : dsf;
    const int boff = br * 64;

    float a[16];
#pragma unroll
    for (int s = 0; s < 16; s++) a[s] = -__expf(Alog[d * DS + s]);
    float Dv = Dp[d];

    size_t base = ((((size_t)br * 4 + b) * NCH + c) * DI + d);
    float h[16];
#pragma unroll
    for (int s = 0; s < 16; s++) h[s] = h_start[base * 16 + s];

    float* yst = br ? yb : yf;
    const int yld = br ? DI : (2 * DI);  // yf lives in xz x-half (stride 2048)

    const size_t rowbase = (size_t)b * L_SEQ;
    const int lstart = br ? (L_SEQ - 1 - c * LC) : (c * LC);
    const int dl = br ? -1 : 1;

    size_t r0 = rowbase + lstart;
    float dt = dt_buf[r0 * DI + d];
    float xc = xc_buf[r0 * DI + d];
    float zv = xz[r0 * (2 * DI) + DI + d];

    for (int i = 0; i < LC; i++) {
        size_t r = rowbase + lstart + i * dl;
        float dt_n = 0.f, xc_n = 0.f, zv_n = 0.f;
        if (i < LC - 1) {
            size_t rn = rowbase + lstart + (i + 1) * dl;
            dt_n = dt_buf[rn * DI + d];
            xc_n = xc_buf[rn * DI + d];
            zv_n = xz[rn * (2 * DI) + DI + d];
        }
        const float* brow = xdbl + r * 128 + boff + 32;  // wave-uniform
        const float* crow = brow + 16;                   // wave-uniform
        float w = dt * xc;
        float p0 = 0.f, p1 = 0.f;
#pragma unroll
        for (int s = 0; s < 16; s += 2) {
            float e0 = __expf(dt * a[s]);
            h[s] = e0 * h[s] + w * brow[s];
            p0 += h[s] * crow[s];
            float e1 = __expf(dt * a[s + 1]);
            h[s + 1] = e1 * h[s + 1] + w * brow[s + 1];
            p1 += h[s + 1] * crow[s + 1];
        }
        float y = (p0 + p1 + xc * Dv) * siluf(zv);
        yst[r * (size_t)yld + d] = y;
        dt = dt_n; xc = xc_n; zv = zv_n;
    }
}

extern "C" void kernel_launch(void* const* d_in, const int* in_sizes, int n_in,
                              void* d_out, int out_size, void* d_ws, size_t ws_size,
                              hipStream_t stream)
{
    const float* hs   = (const float*)d_in[0];
    const float* nw   = (const float*)d_in[1];
    const float* nbp  = (const float*)d_in[2];
    const float* ipw  = (const float*)d_in[3];
    const float* opw  = (const float*)d_in[4];
    const float* cwf  = (const float*)d_in[5];
    const float* cbf  = (const float*)d_in[6];
    const float* xpwf = (const float*)d_in[7];
    const float* dtwf = (const float*)d_in[8];
    const float* dtbf = (const float*)d_in[9];
    const float* alf  = (const float*)d_in[10];
    const float* dsf  = (const float*)d_in[11];
    const float* cwb  = (const float*)d_in[12];
    const float* cbb  = (const float*)d_in[13];
    const float* xpwb = (const float*)d_in[14];
    const float* dtwb = (const float*)d_in[15];
    const float* dtbb = (const float*)d_in[16];
    const float* alb  = (const float*)d_in[17];
    const float* dsb  = (const float*)d_in[18];

    float* out   = (float*)d_out;                       // [8192][512]
    float* resid = out + (size_t)MROWS * DM;            // [8192][512]

    // ws layout (fp32), ~245 MiB
    float* ws = (float*)d_ws;
    float* h     = ws;  ws += (size_t)MROWS * DM;       // 16MB; dead after gemm1 -> q_buf alias
    float* xz    = ws;  ws += (size_t)MROWS * 2 * DI;   // 64MB (x | z); x-half becomes y_f
    float* xcf   = ws;  ws += (size_t)MROWS * DI;
    float* xcb   = ws;  ws += (size_t)MROWS * DI;
    float* dtfb  = ws;  ws += (size_t)MROWS * DI;
    float* dtbb_ = ws;  ws += (size_t)MROWS * DI;
    float* xdbl  = ws;  ws += (size_t)MROWS * 128;      // [fwd 64 | bwd 64]
    float* yb    = ws;  ws += (size_t)MROWS * DI;
    float* dtsum = ws;  ws += (size_t)2 * NB * NCH * DI; // 1MB
    float* yf    = xz;                                  // stride 2048, cols 0..1023
    float* q_buf = h;                                   // 16MB, exact size match
    float* h_st  = out;                                 // d_out front half as scratch; overwritten by final gemm

    ln_kernel<<<MROWS, 256, 0, stream>>>(hs, nw, nbp, h, resid);

    // xz = h @ in_proj_w^T   (M=8192, N=2048, K=512)
    gemm_nt<0, 0><<<dim3(2 * DI / 64, MROWS / 64), 256, 0, stream>>>(
        h, DM, nullptr, 0, ipw, DM, nullptr, xz, 2 * DI, DM, 1.f);

    conv_kernel<<<MROWS, 256, 0, stream>>>(xz, cwf, cbf, cwb, cbb, xcf, xcb);

    // x_dbl = xc @ x_proj_w^T  (N=64, K=1024), per branch
    gemm_nt<0, 0><<<dim3(1, MROWS / 64), 256, 0, stream>>>(
        xcf, DI, nullptr, 0, xpwf, DI, nullptr, xdbl, 128, DI, 1.f);
    gemm_nt<0, 0><<<dim3(1, MROWS / 64), 256, 0, stream>>>(
        xcb, DI, nullptr, 0, xpwb, DI, nullptr, xdbl + 64, 128, DI, 1.f);

    // dt = softplus(x_dbl[:, :32] @ dt_proj_w^T + b)  (N=1024, K=32), per branch
    gemm_nt<0, 1><<<dim3(DI / 64, MROWS / 64), 256, 0, stream>>>(
        xdbl, 128, nullptr, 0, dtwf, DTR, dtbf, dtfb, DI, DTR, 1.f);
    gemm_nt<0, 1><<<dim3(DI / 64, MROWS / 64), 256, 0, stream>>>(
        xdbl + 64, 128, nullptr, 0, dtwb, DTR, dtbb, dtbb_, DI, DTR, 1.f);

    // chunked selective scan, both directions in each launch
    scan_pass1<<<2 * NB * NCH * (DI / 256), 256, 0, stream>>>(
        xcf, xcb, dtfb, dtbb_, xdbl, alf, alb, q_buf, dtsum);
    scan_pass2<<<(2 * NB * DI) / 16, 256, 0, stream>>>(
        q_buf, dtsum, alf, alb, h_st);
    scan_pass3<<<2 * NB * NCH * (DI / 256), 256, 0, stream>>>(
        xz, xcf, xcb, dtfb, dtbb_, xdbl, alf, alb, dsf, dsb, h_st, yf, yb);

    // out = (y_f + y_b) @ out_proj_w^T * 0.5  (N=512, K=1024)
    gemm_nt<1, 0><<<dim3(DM / 64, MROWS / 64), 256, 0, stream>>>(
        yf, 2 * DI, yb, DI, opw, DI, nullptr, out, DM, DI, 0.5f);
}

// Round 3
// 528.203 us; speedup vs baseline: 2.8860x; 1.6914x over previous
//
#include <hip/hip_runtime.h>
#include <math.h>

#define L_SEQ 2048
#define NB 4
#define DM 512
#define DI 1024
#define DS 16
#define DTR 32
#define MROWS (NB * L_SEQ)  // 8192
#define LC 64               // chunk length
#define NCH 32              // chunks per sequence

typedef __attribute__((ext_vector_type(8))) short bf16x8;
typedef __attribute__((ext_vector_type(4))) float f32x4;

__device__ __forceinline__ float siluf(float x) { return x / (1.f + __expf(-x)); }
__device__ __forceinline__ float softplusf(float x) { return x > 20.f ? x : log1pf(expf(x)); }
__device__ __forceinline__ unsigned short f2bf(float x) {
    unsigned int u = __float_as_uint(x);
    u += 0x7fffu + ((u >> 16) & 1u);
    return (unsigned short)(u >> 16);
}

// ---------------- fp32 -> bf16 cast ----------------
__global__ __launch_bounds__(256)
void cast_bf16(const float* __restrict__ src, unsigned short* __restrict__ dst, int n)
{
    int i = (blockIdx.x * 256 + threadIdx.x) * 4;
    if (i >= n) return;
    float4 v = *(const float4*)(src + i);
    ushort4 o;
    o.x = f2bf(v.x); o.y = f2bf(v.y); o.z = f2bf(v.z); o.w = f2bf(v.w);
    *(ushort4*)(dst + i) = o;
}

// ---------------- LayerNorm + residual copy; h written as bf16 ----------------
__global__ __launch_bounds__(256)
void ln_kernel(const float* __restrict__ hs, const float* __restrict__ nw,
               const float* __restrict__ nb, unsigned short* __restrict__ h_bf,
               float* __restrict__ resid)
{
    int r = blockIdx.x;
    int tid = threadIdx.x;
    const float2* rp = (const float2*)(hs + (size_t)r * DM);
    float2 v = rp[tid];
    float s1 = v.x + v.y;
    float s2 = v.x * v.x + v.y * v.y;
#pragma unroll
    for (int off = 32; off >= 1; off >>= 1) {
        s1 += __shfl_down(s1, off);
        s2 += __shfl_down(s2, off);
    }
    __shared__ float r1[4], r2[4];
    int wid = tid >> 6, lane = tid & 63;
    if (lane == 0) { r1[wid] = s1; r2[wid] = s2; }
    __syncthreads();
    s1 = r1[0] + r1[1] + r1[2] + r1[3];
    s2 = r2[0] + r2[1] + r2[2] + r2[3];
    float mean = s1 * (1.f / DM);
    float var = s2 * (1.f / DM) - mean * mean;
    float rstd = rsqrtf(var + 1e-5f);
    float2 w = ((const float2*)nw)[tid];
    float2 bb = ((const float2*)nb)[tid];
    float ox = (v.x - mean) * rstd * w.x + bb.x;
    float oy = (v.y - mean) * rstd * w.y + bb.y;
    unsigned int pack = (unsigned int)f2bf(ox) | ((unsigned int)f2bf(oy) << 16);
    ((unsigned int*)h_bf)[(size_t)r * (DM / 2) + tid] = pack;
    ((float2*)(resid + (size_t)r * DM))[tid] = v;
}

// ---------------- bf16 MFMA GEMM: C[m,n] = scale * sum_k A[m,k]*B[n,k] ----------------
// 128x128 tile, BK=32, 256 threads (4 waves 2x2), 4x4 16x16x32 frags per wave.
// global_load_lds width-16 staging; LDS row-major [128][32] bf16.
__global__ __launch_bounds__(256)
void gemm_bf16mm(const unsigned short* __restrict__ A, int lda,
                 const unsigned short* __restrict__ B, int ldb,
                 float* __restrict__ C, int ldc, int K, float scale)
{
    __shared__ unsigned short sA[128 * 32];
    __shared__ unsigned short sB[128 * 32];
    const int tid = threadIdx.x;
    const int lane = tid & 63;
    const int w = tid >> 6;
    const int wr = w >> 1, wc = w & 1;
    const size_t bm = (size_t)blockIdx.y * 128;
    const size_t bn = (size_t)blockIdx.x * 128;

    f32x4 acc[4][4];
#pragma unroll
    for (int i = 0; i < 4; i++)
#pragma unroll
        for (int j = 0; j < 4; j++) acc[i][j] = (f32x4){0.f, 0.f, 0.f, 0.f};

    const int r4 = lane >> 2;        // 0..15
    const int c8 = (lane & 3) * 8;   // bf16 col offset within 32
    const int rl = lane & 15;
    const int kq = (lane >> 4) * 8;

    for (int k0 = 0; k0 < K; k0 += 32) {
        __syncthreads();
#pragma unroll
        for (int i = 0; i < 2; i++) {
            int row = i * 64 + w * 16 + r4;
            const unsigned short* ga = A + (bm + row) * (size_t)lda + k0 + c8;
            char* la = (char*)sA + i * 4096 + w * 1024;
            __builtin_amdgcn_global_load_lds((const __attribute__((address_space(1))) void*)ga,
                                             (__attribute__((address_space(3))) void*)la, 16, 0, 0);
            const unsigned short* gb = B + (bn + row) * (size_t)ldb + k0 + c8;
            char* lb = (char*)sB + i * 4096 + w * 1024;
            __builtin_amdgcn_global_load_lds((const __attribute__((address_space(1))) void*)gb,
                                             (__attribute__((address_space(3))) void*)lb, 16, 0, 0);
        }
        __syncthreads();

        bf16x8 af[4], bfr[4];
#pragma unroll
        for (int t = 0; t < 4; t++) {
            af[t]  = *(const bf16x8*)&sA[(wr * 64 + t * 16 + rl) * 32 + kq];
            bfr[t] = *(const bf16x8*)&sB[(wc * 64 + t * 16 + rl) * 32 + kq];
        }
#pragma unroll
        for (int mt = 0; mt < 4; mt++)
#pragma unroll
            for (int nt = 0; nt < 4; nt++)
                acc[mt][nt] = __builtin_amdgcn_mfma_f32_16x16x32_bf16(af[mt], bfr[nt], acc[mt][nt], 0, 0, 0);
    }

    const int rq = lane >> 4;
#pragma unroll
    for (int mt = 0; mt < 4; mt++) {
#pragma unroll
        for (int nt = 0; nt < 4; nt++) {
#pragma unroll
            for (int j = 0; j < 4; j++) {
                size_t m = bm + wr * 64 + mt * 16 + rq * 4 + j;
                size_t n = bn + wc * 64 + nt * 16 + rl;
                C[m * (size_t)ldc + n] = acc[mt][nt][j] * scale;
            }
        }
    }
}

// ---------------- fp32 NT GEMM with blockIdx.z branch select ----------------
template <int SP>
__global__ __launch_bounds__(256)
void gemm_nt2(const float* __restrict__ A0, const float* __restrict__ A1, int lda,
              const float* __restrict__ B0, const float* __restrict__ B1, int ldb,
              const float* __restrict__ bias0, const float* __restrict__ bias1,
              float* __restrict__ C0, float* __restrict__ C1, int ldc,
              int K, float scale)
{
    const float* A = blockIdx.z ? A1 : A0;
    const float* B = blockIdx.z ? B1 : B0;
    const float* bias = blockIdx.z ? bias1 : bias0;
    float* C = blockIdx.z ? C1 : C0;

    __shared__ float sA[16][64];
    __shared__ float sB[16][64];
    const int tid = threadIdx.x;
    const size_t bm = (size_t)blockIdx.y * 64;
    const size_t bn = (size_t)blockIdx.x * 64;
    const int lr = tid >> 2;
    const int lc = (tid & 3) << 2;
    const int tx = tid & 15;
    const int ty = tid >> 4;
    float acc[4][4];
#pragma unroll
    for (int i = 0; i < 4; i++)
#pragma unroll
        for (int j = 0; j < 4; j++) acc[i][j] = 0.f;

    const float* aptr = A + (bm + lr) * (size_t)lda + lc;
    const float* bptr = B + (bn + lr) * (size_t)ldb + lc;

    for (int k0 = 0; k0 < K; k0 += 16) {
        float4 av = *(const float4*)(aptr + k0);
        float4 bv = *(const float4*)(bptr + k0);
        sA[lc + 0][lr] = av.x; sA[lc + 1][lr] = av.y; sA[lc + 2][lr] = av.z; sA[lc + 3][lr] = av.w;
        sB[lc + 0][lr] = bv.x; sB[lc + 1][lr] = bv.y; sB[lc + 2][lr] = bv.z; sB[lc + 3][lr] = bv.w;
        __syncthreads();
#pragma unroll
        for (int kk = 0; kk < 16; kk++) {
            float4 a = *(const float4*)&sA[kk][ty << 2];
            float4 b = *(const float4*)&sB[kk][tx << 2];
            acc[0][0] += a.x * b.x; acc[0][1] += a.x * b.y; acc[0][2] += a.x * b.z; acc[0][3] += a.x * b.w;
            acc[1][0] += a.y * b.x; acc[1][1] += a.y * b.y; acc[1][2] += a.y * b.z; acc[1][3] += a.y * b.w;
            acc[2][0] += a.z * b.x; acc[2][1] += a.z * b.y; acc[2][2] += a.z * b.z; acc[2][3] += a.z * b.w;
            acc[3][0] += a.w * b.x; acc[3][1] += a.w * b.y; acc[3][2] += a.w * b.z; acc[3][3] += a.w * b.w;
        }
        __syncthreads();
    }
#pragma unroll
    for (int i = 0; i < 4; i++) {
        size_t m = bm + (ty << 2) + i;
#pragma unroll
        for (int j = 0; j < 4; j++) {
            size_t n = bn + (tx << 2) + j;
            float v = acc[i][j] * scale;
            if (SP) v = softplusf(v + bias[n]);
            C[m * (size_t)ldc + n] = v;
        }
    }
}

// ---------------- Depthwise causal (fwd) + anti-causal (bwd) conv + SiLU ----------------
__global__ __launch_bounds__(256)
void conv_kernel(const float* __restrict__ xz,
                 const float* __restrict__ cwf, const float* __restrict__ cbf,
                 const float* __restrict__ cwb, const float* __restrict__ cbb,
                 float* __restrict__ xcf, float* __restrict__ xcb)
{
    int r = blockIdx.x;           // 0..8191
    int b = r >> 11, l = r & (L_SEQ - 1);
    int tid = threadIdx.x;
#pragma unroll
    for (int i = 0; i < 4; i++) {
        int d = tid + (i << 8);
        float accf = cbf[d], accb = cbb[d];
#pragma unroll
        for (int k = 0; k < 4; k++) {
            int lf = l - 3 + k;
            if (lf >= 0)
                accf += xz[((size_t)(b * L_SEQ + lf)) * (2 * DI) + d] * cwf[(d << 2) + k];
            int lb = l + k;
            if (lb < L_SEQ)
                accb += xz[((size_t)(b * L_SEQ + lb)) * (2 * DI) + d] * cwb[(d << 2) + 3 - k];
        }
        xcf[(size_t)r * DI + d] = siluf(accf);
        xcb[(size_t)r * DI + d] = siluf(accb);
    }
}

// ---------------- Chunked selective scan ----------------
__global__ __launch_bounds__(256)
void scan_pass1(const float* __restrict__ xcf, const float* __restrict__ xcb,
                const float* __restrict__ dtf, const float* __restrict__ dtb,
                const float* __restrict__ xdbl,
                const float* __restrict__ alf, const float* __restrict__ alb,
                float* __restrict__ q_buf, float* __restrict__ dtsum_buf)
{
    const int bid = blockIdx.x;
    const int d  = ((bid & 3) << 8) + threadIdx.x;
    const int c  = (bid >> 2) & 31;
    const int b  = (bid >> 7) & 3;
    const int br = bid >> 9;

    const float* xc_buf = br ? xcb : xcf;
    const float* dt_buf = br ? dtb : dtf;
    const float* Alog   = br ? alb : alf;
    const int boff = br * 64;

    float a[16];
#pragma unroll
    for (int s = 0; s < 16; s++) a[s] = -__expf(Alog[d * DS + s]);

    float h[16];
#pragma unroll
    for (int s = 0; s < 16; s++) h[s] = 0.f;
    float Dt = 0.f;

    const size_t rowbase = (size_t)b * L_SEQ;
    const int lstart = br ? (L_SEQ - 1 - c * LC) : (c * LC);
    const int dl = br ? -1 : 1;

    size_t r0 = rowbase + lstart;
    float dt = dt_buf[r0 * DI + d];
    float xc = xc_buf[r0 * DI + d];

    for (int i = 0; i < LC; i++) {
        size_t r = rowbase + lstart + i * dl;
        float dt_n = 0.f, xc_n = 0.f;
        if (i < LC - 1) {
            size_t rn = rowbase + lstart + (i + 1) * dl;
            dt_n = dt_buf[rn * DI + d];
            xc_n = xc_buf[rn * DI + d];
        }
        const float* brow = xdbl + r * 128 + boff + 32;  // wave-uniform
        float w = dt * xc;
        Dt += dt;
#pragma unroll
        for (int s = 0; s < 16; s++) {
            float e = __expf(dt * a[s]);
            h[s] = e * h[s] + w * brow[s];
        }
        dt = dt_n; xc = xc_n;
    }

    size_t base = ((((size_t)br * 4 + b) * NCH + c) * DI + d);
#pragma unroll
    for (int s = 0; s < 16; s++) q_buf[base * 16 + s] = h[s];
    dtsum_buf[base] = Dt;
}

__global__ __launch_bounds__(256)
void scan_pass2(const float* __restrict__ q_buf, const float* __restrict__ dtsum_buf,
                const float* __restrict__ alf, const float* __restrict__ alb,
                float* __restrict__ h_start)
{
    int idx = blockIdx.x * 16 + (threadIdx.x >> 4);  // channel 0..8191
    int s = threadIdx.x & 15;
    int br = idx >> 12;
    int b  = (idx >> 10) & 3;
    int d  = idx & 1023;
    const float* Alog = br ? alb : alf;
    float a = -__expf(Alog[d * DS + s]);
    float h = 0.f;
    for (int c = 0; c < NCH; c++) {
        size_t base = ((((size_t)br * 4 + b) * NCH + c) * DI + d);
        h_start[base * 16 + s] = h;
        float Dt = dtsum_buf[base];
        float qv = q_buf[base * 16 + s];
        h = __expf(a * Dt) * h + qv;
    }
}

__global__ __launch_bounds__(256)
void scan_pass3(const float* __restrict__ xz,
                const float* __restrict__ xcf, const float* __restrict__ xcb,
                const float* __restrict__ dtf, const float* __restrict__ dtb,
                const float* __restrict__ xdbl,
                const float* __restrict__ alf, const float* __restrict__ alb,
                const float* __restrict__ dsf, const float* __restrict__ dsb,
                const float* __restrict__ h_start,
                float* __restrict__ yf, float* __restrict__ yb)
{
    const int bid = blockIdx.x;
    const int d  = ((bid & 3) << 8) + threadIdx.x;
    const int c  = (bid >> 2) & 31;
    const int b  = (bid >> 7) & 3;
    const int br = bid >> 9;

    const float* xc_buf = br ? xcb : xcf;
    const float* dt_buf = br ? dtb : dtf;
    const float* Alog   = br ? alb : alf;
    const float* Dp     = br ? dsb : dsf;
    const int boff = br * 64;

    float a[16];
#pragma unroll
    for (int s = 0; s < 16; s++) a[s] = -__expf(Alog[d * DS + s]);
    float Dv = Dp[d];

    size_t base = ((((size_t)br * 4 + b) * NCH + c) * DI + d);
    float h[16];
#pragma unroll
    for (int s = 0; s < 16; s++) h[s] = h_start[base * 16 + s];

    float* yst = br ? yb : yf;
    const int yld = br ? DI : (2 * DI);  // yf lives in xz x-half (stride 2048)

    const size_t rowbase = (size_t)b * L_SEQ;
    const int lstart = br ? (L_SEQ - 1 - c * LC) : (c * LC);
    const int dl = br ? -1 : 1;

    size_t r0 = rowbase + lstart;
    float dt = dt_buf[r0 * DI + d];
    float xc = xc_buf[r0 * DI + d];
    float zv = xz[r0 * (2 * DI) + DI + d];

    for (int i = 0; i < LC; i++) {
        size_t r = rowbase + lstart + i * dl;
        float dt_n = 0.f, xc_n = 0.f, zv_n = 0.f;
        if (i < LC - 1) {
            size_t rn = rowbase + lstart + (i + 1) * dl;
            dt_n = dt_buf[rn * DI + d];
            xc_n = xc_buf[rn * DI + d];
            zv_n = xz[rn * (2 * DI) + DI + d];
        }
        const float* brow = xdbl + r * 128 + boff + 32;  // wave-uniform
        const float* crow = brow + 16;                   // wave-uniform
        float w = dt * xc;
        float p0 = 0.f, p1 = 0.f;
#pragma unroll
        for (int s = 0; s < 16; s += 2) {
            float e0 = __expf(dt * a[s]);
            h[s] = e0 * h[s] + w * brow[s];
            p0 += h[s] * crow[s];
            float e1 = __expf(dt * a[s + 1]);
            h[s + 1] = e1 * h[s + 1] + w * brow[s + 1];
            p1 += h[s + 1] * crow[s + 1];
        }
        float y = (p0 + p1 + xc * Dv) * siluf(zv);
        yst[r * (size_t)yld + d] = y;
        dt = dt_n; xc = xc_n; zv = zv_n;
    }
}

// ---------------- y_f + y_b -> bf16 ----------------
__global__ __launch_bounds__(256)
void ycombine(const float* __restrict__ yf, const float* __restrict__ yb,
              unsigned short* __restrict__ ybf)
{
    int r = blockIdx.x;
    int t = threadIdx.x;
    float4 a = ((const float4*)(yf + (size_t)r * 2 * DI))[t];
    float4 b = ((const float4*)(yb + (size_t)r * DI))[t];
    ushort4 o;
    o.x = f2bf(a.x + b.x); o.y = f2bf(a.y + b.y);
    o.z = f2bf(a.z + b.z); o.w = f2bf(a.w + b.w);
    ((ushort4*)(ybf + (size_t)r * DI))[t] = o;
}

extern "C" void kernel_launch(void* const* d_in, const int* in_sizes, int n_in,
                              void* d_out, int out_size, void* d_ws, size_t ws_size,
                              hipStream_t stream)
{
    const float* hs   = (const float*)d_in[0];
    const float* nw   = (const float*)d_in[1];
    const float* nbp  = (const float*)d_in[2];
    const float* ipw  = (const float*)d_in[3];
    const float* opw  = (const float*)d_in[4];
    const float* cwf  = (const float*)d_in[5];
    const float* cbf  = (const float*)d_in[6];
    const float* xpwf = (const float*)d_in[7];
    const float* dtwf = (const float*)d_in[8];
    const float* dtbf = (const float*)d_in[9];
    const float* alf  = (const float*)d_in[10];
    const float* dsf  = (const float*)d_in[11];
    const float* cwb  = (const float*)d_in[12];
    const float* cbb  = (const float*)d_in[13];
    const float* xpwb = (const float*)d_in[14];
    const float* dtwb = (const float*)d_in[15];
    const float* dtbb = (const float*)d_in[16];
    const float* alb  = (const float*)d_in[17];
    const float* dsb  = (const float*)d_in[18];

    float* out   = (float*)d_out;                       // [8192][512]
    float* resid = out + (size_t)MROWS * DM;            // [8192][512]

    // ws layout (~248 MiB)
    float* ws = (float*)d_ws;
    float* hq    = ws;  ws += (size_t)MROWS * DM;       // h_bf (first 8MB) then q_buf (16MB); disjoint lifetimes
    float* xz    = ws;  ws += (size_t)MROWS * 2 * DI;   // x | z; x-half becomes y_f
    float* xcf   = ws;  ws += (size_t)MROWS * DI;       // later: ybf (first 16MB)
    float* xcb   = ws;  ws += (size_t)MROWS * DI;
    float* dtfb  = ws;  ws += (size_t)MROWS * DI;
    float* dtbb_ = ws;  ws += (size_t)MROWS * DI;
    float* xdbl  = ws;  ws += (size_t)MROWS * 128;      // [fwd 64 | bwd 64]
    float* yb    = ws;  ws += (size_t)MROWS * DI;
    float* dtsum = ws;  ws += (size_t)2 * NB * NCH * DI;
    unsigned short* ipw_bf = (unsigned short*)ws; ws += (size_t)(2 * DI) * DM / 2;
    unsigned short* opw_bf = (unsigned short*)ws; ws += (size_t)DM * DI / 2;

    unsigned short* h_bf = (unsigned short*)hq;
    float* q_buf = hq;
    unsigned short* ybf = (unsigned short*)xcf;
    float* yf   = xz;                                   // stride 2048, cols 0..1023
    float* h_st = out;                                  // scratch; overwritten by final gemm

    cast_bf16<<<(2 * DI * DM) / 1024, 256, 0, stream>>>(ipw, ipw_bf, 2 * DI * DM);
    cast_bf16<<<(DM * DI) / 1024, 256, 0, stream>>>(opw, opw_bf, DM * DI);

    ln_kernel<<<MROWS, 256, 0, stream>>>(hs, nw, nbp, h_bf, resid);

    // xz = h @ in_proj_w^T   (M=8192, N=2048, K=512), bf16 MFMA
    gemm_bf16mm<<<dim3((2 * DI) / 128, MROWS / 128), 256, 0, stream>>>(
        h_bf, DM, ipw_bf, DM, xz, 2 * DI, DM, 1.f);

    conv_kernel<<<MROWS, 256, 0, stream>>>(xz, cwf, cbf, cwb, cbb, xcf, xcb);

    // x_dbl = xc @ x_proj_w^T  (N=64, K=1024), both branches in one launch
    gemm_nt2<0><<<dim3(1, MROWS / 64, 2), 256, 0, stream>>>(
        xcf, xcb, DI, xpwf, xpwb, DI, nullptr, nullptr, xdbl, xdbl + 64, 128, DI, 1.f);

    // dt = softplus(x_dbl[:, :32] @ dt_proj_w^T + b)  (N=1024, K=32), both branches
    gemm_nt2<1><<<dim3(DI / 64, MROWS / 64, 2), 256, 0, stream>>>(
        xdbl, xdbl + 64, 128, dtwf, dtwb, DTR, dtbf, dtbb, dtfb, dtbb_, DI, DTR, 1.f);

    // chunked selective scan
    scan_pass1<<<2 * NB * NCH * (DI / 256), 256, 0, stream>>>(
        xcf, xcb, dtfb, dtbb_, xdbl, alf, alb, q_buf, dtsum);
    scan_pass2<<<(2 * NB * DI) / 16, 256, 0, stream>>>(
        q_buf, dtsum, alf, alb, h_st);
    scan_pass3<<<2 * NB * NCH * (DI / 256), 256, 0, stream>>>(
        xz, xcf, xcb, dtfb, dtbb_, xdbl, alf, alb, dsf, dsb, h_st, yf, yb);

    // ybf = bf16(y_f + y_b)
    ycombine<<<MROWS, 256, 0, stream>>>(yf, yb, ybf);

    // out = ybf @ out_proj_w^T * 0.5  (M=8192, N=512, K=1024), bf16 MFMA
    gemm_bf16mm<<<dim3(DM / 128, MROWS / 128), 256, 0, stream>>>(
        ybf, DI, opw_bf, DI, out, DM, DI, 0.5f);
}

// Round 4
// 468.955 us; speedup vs baseline: 3.2507x; 1.1263x over previous
//
#include <hip/hip_runtime.h>
#include <math.h>

#define L_SEQ 2048
#define NB 4
#define DM 512
#define DI 1024
#define DS 16
#define DTR 32
#define MROWS (NB * L_SEQ)  // 8192
#define LC 64               // chunk length
#define NCH 32              // chunks per sequence
#define KS 4                // K-split for xproj

typedef __attribute__((ext_vector_type(8))) short bf16x8;
typedef __attribute__((ext_vector_type(4))) float f32x4;

__device__ __forceinline__ float siluf(float x) { return x / (1.f + __expf(-x)); }
__device__ __forceinline__ float softplusf(float x) { return x > 20.f ? x : log1pf(expf(x)); }
__device__ __forceinline__ unsigned short f2bf(float x) {
    unsigned int u = __float_as_uint(x);
    u += 0x7fffu + ((u >> 16) & 1u);
    return (unsigned short)(u >> 16);
}
__device__ __forceinline__ float bf2f(unsigned short u) {
    return __uint_as_float(((unsigned int)u) << 16);
}

// ---------------- fp32 -> bf16 cast ----------------
__global__ __launch_bounds__(256)
void cast_bf16(const float* __restrict__ src, unsigned short* __restrict__ dst, int n)
{
    int i = (blockIdx.x * 256 + threadIdx.x) * 4;
    if (i >= n) return;
    float4 v = *(const float4*)(src + i);
    ushort4 o;
    o.x = f2bf(v.x); o.y = f2bf(v.y); o.z = f2bf(v.z); o.w = f2bf(v.w);
    *(ushort4*)(dst + i) = o;
}

// ---------------- LayerNorm + residual copy; h written as bf16 ----------------
__global__ __launch_bounds__(256)
void ln_kernel(const float* __restrict__ hs, const float* __restrict__ nw,
               const float* __restrict__ nb, unsigned short* __restrict__ h_bf,
               float* __restrict__ resid)
{
    int r = blockIdx.x;
    int tid = threadIdx.x;
    const float2* rp = (const float2*)(hs + (size_t)r * DM);
    float2 v = rp[tid];
    float s1 = v.x + v.y;
    float s2 = v.x * v.x + v.y * v.y;
#pragma unroll
    for (int off = 32; off >= 1; off >>= 1) {
        s1 += __shfl_down(s1, off);
        s2 += __shfl_down(s2, off);
    }
    __shared__ float r1[4], r2[4];
    int wid = tid >> 6, lane = tid & 63;
    if (lane == 0) { r1[wid] = s1; r2[wid] = s2; }
    __syncthreads();
    s1 = r1[0] + r1[1] + r1[2] + r1[3];
    s2 = r2[0] + r2[1] + r2[2] + r2[3];
    float mean = s1 * (1.f / DM);
    float var = s2 * (1.f / DM) - mean * mean;
    float rstd = rsqrtf(var + 1e-5f);
    float2 w = ((const float2*)nw)[tid];
    float2 bb = ((const float2*)nb)[tid];
    float ox = (v.x - mean) * rstd * w.x + bb.x;
    float oy = (v.y - mean) * rstd * w.y + bb.y;
    unsigned int pack = (unsigned int)f2bf(ox) | ((unsigned int)f2bf(oy) << 16);
    ((unsigned int*)h_bf)[(size_t)r * (DM / 2) + tid] = pack;
    ((float2*)(resid + (size_t)r * DM))[tid] = v;
}

// ---------------- bf16 MFMA GEMM: C[m,n] = scale * sum_k A[m,k]*B[n,k] ----------------
// 128x128 tile, BK=32, 256 threads (4 waves 2x2), 4x4 16x16x32 frags per wave.
// DUAL: A-tile = bf16(A + A2), reg-staged. OUTBF: C written bf16, else fp32.
template <int DUAL, int OUTBF>
__global__ __launch_bounds__(256)
void gemm_bf16mm(const unsigned short* __restrict__ A,
                 const unsigned short* __restrict__ A2, int lda,
                 const unsigned short* __restrict__ B, int ldb,
                 void* __restrict__ Cv, int ldc, int K, float scale)
{
    __shared__ unsigned short sA[128 * 32];
    __shared__ unsigned short sB[128 * 32];
    const int tid = threadIdx.x;
    const int lane = tid & 63;
    const int w = tid >> 6;
    const int wr = w >> 1, wc = w & 1;
    const size_t bm = (size_t)blockIdx.y * 128;
    const size_t bn = (size_t)blockIdx.x * 128;

    f32x4 acc[4][4];
#pragma unroll
    for (int i = 0; i < 4; i++)
#pragma unroll
        for (int j = 0; j < 4; j++) acc[i][j] = (f32x4){0.f, 0.f, 0.f, 0.f};

    const int r4 = lane >> 2;        // 0..15
    const int c8 = (lane & 3) * 8;   // bf16 col offset within 32
    const int rl = lane & 15;
    const int kq = (lane >> 4) * 8;

    for (int k0 = 0; k0 < K; k0 += 32) {
        __syncthreads();
#pragma unroll
        for (int i = 0; i < 2; i++) {
            int row = i * 64 + w * 16 + r4;
            if (DUAL) {
                bf16x8 a1 = *(const bf16x8*)(A  + (bm + row) * (size_t)lda + k0 + c8);
                bf16x8 a2 = *(const bf16x8*)(A2 + (bm + row) * (size_t)lda + k0 + c8);
                bf16x8 s;
#pragma unroll
                for (int j = 0; j < 8; j++)
                    s[j] = (short)f2bf(bf2f((unsigned short)a1[j]) + bf2f((unsigned short)a2[j]));
                *(bf16x8*)((char*)sA + i * 4096 + w * 1024 + lane * 16) = s;
            } else {
                const unsigned short* ga = A + (bm + row) * (size_t)lda + k0 + c8;
                char* la = (char*)sA + i * 4096 + w * 1024;
                __builtin_amdgcn_global_load_lds((const __attribute__((address_space(1))) void*)ga,
                                                 (__attribute__((address_space(3))) void*)la, 16, 0, 0);
            }
            const unsigned short* gb = B + (bn + row) * (size_t)ldb + k0 + c8;
            char* lb = (char*)sB + i * 4096 + w * 1024;
            __builtin_amdgcn_global_load_lds((const __attribute__((address_space(1))) void*)gb,
                                             (__attribute__((address_space(3))) void*)lb, 16, 0, 0);
        }
        __syncthreads();

        bf16x8 af[4], bfr[4];
#pragma unroll
        for (int t = 0; t < 4; t++) {
            af[t]  = *(const bf16x8*)&sA[(wr * 64 + t * 16 + rl) * 32 + kq];
            bfr[t] = *(const bf16x8*)&sB[(wc * 64 + t * 16 + rl) * 32 + kq];
        }
#pragma unroll
        for (int mt = 0; mt < 4; mt++)
#pragma unroll
            for (int nt = 0; nt < 4; nt++)
                acc[mt][nt] = __builtin_amdgcn_mfma_f32_16x16x32_bf16(af[mt], bfr[nt], acc[mt][nt], 0, 0, 0);
    }

    const int rq = lane >> 4;
#pragma unroll
    for (int mt = 0; mt < 4; mt++) {
#pragma unroll
        for (int nt = 0; nt < 4; nt++) {
#pragma unroll
            for (int j = 0; j < 4; j++) {
                size_t m = bm + wr * 64 + mt * 16 + rq * 4 + j;
                size_t n = bn + wc * 64 + nt * 16 + rl;
                float v = acc[mt][nt][j] * scale;
                if (OUTBF) ((unsigned short*)Cv)[m * (size_t)ldc + n] = f2bf(v);
                else       ((float*)Cv)[m * (size_t)ldc + n] = v;
            }
        }
    }
}

// ---------------- xproj MFMA: part[kz][m][br*64+n] = sum_{k in chunk} xc[m,k]*w[n,k] ----------------
// grid (KS, MROWS/128, 2). Tile M=128, N=64, Kchunk=256. 4 waves stacked on M (32 rows each).
__global__ __launch_bounds__(256)
void xproj_mfma(const unsigned short* __restrict__ xcf, const unsigned short* __restrict__ xcb,
                const unsigned short* __restrict__ wf, const unsigned short* __restrict__ wb,
                float* __restrict__ part)
{
    const int kz = blockIdx.x;
    const int br = blockIdx.z;
    const size_t bm = (size_t)blockIdx.y * 128;
    const unsigned short* A = br ? xcb : xcf;
    const unsigned short* B = br ? wb : wf;

    __shared__ unsigned short sA[128 * 32];
    __shared__ unsigned short sB[64 * 32];
    const int tid = threadIdx.x;
    const int lane = tid & 63;
    const int w = tid >> 6;
    const int r4 = lane >> 2;
    const int c8 = (lane & 3) * 8;
    const int rl = lane & 15;
    const int kq = (lane >> 4) * 8;

    f32x4 acc[2][4];
#pragma unroll
    for (int i = 0; i < 2; i++)
#pragma unroll
        for (int j = 0; j < 4; j++) acc[i][j] = (f32x4){0.f, 0.f, 0.f, 0.f};

    for (int ks = 0; ks < 8; ks++) {
        int k0 = kz * 256 + ks * 32;
        __syncthreads();
#pragma unroll
        for (int i = 0; i < 2; i++) {
            int row = i * 64 + w * 16 + r4;
            const unsigned short* ga = A + (bm + row) * (size_t)DI + k0 + c8;
            char* la = (char*)sA + i * 4096 + w * 1024;
            __builtin_amdgcn_global_load_lds((const __attribute__((address_space(1))) void*)ga,
                                             (__attribute__((address_space(3))) void*)la, 16, 0, 0);
        }
        {
            int row = w * 16 + r4;
            const unsigned short* gb = B + row * (size_t)DI + k0 + c8;
            char* lb = (char*)sB + w * 1024;
            __builtin_amdgcn_global_load_lds((const __attribute__((address_space(1))) void*)gb,
                                             (__attribute__((address_space(3))) void*)lb, 16, 0, 0);
        }
        __syncthreads();

        bf16x8 af[2], bfr[4];
#pragma unroll
        for (int t = 0; t < 2; t++)
            af[t] = *(const bf16x8*)&sA[(w * 32 + t * 16 + rl) * 32 + kq];
#pragma unroll
        for (int t = 0; t < 4; t++)
            bfr[t] = *(const bf16x8*)&sB[(t * 16 + rl) * 32 + kq];
#pragma unroll
        for (int mt = 0; mt < 2; mt++)
#pragma unroll
            for (int nt = 0; nt < 4; nt++)
                acc[mt][nt] = __builtin_amdgcn_mfma_f32_16x16x32_bf16(af[mt], bfr[nt], acc[mt][nt], 0, 0, 0);
    }

    const int rq = lane >> 4;
#pragma unroll
    for (int mt = 0; mt < 2; mt++) {
#pragma unroll
        for (int nt = 0; nt < 4; nt++) {
#pragma unroll
            for (int j = 0; j < 4; j++) {
                size_t m = bm + w * 32 + mt * 16 + rq * 4 + j;
                size_t n = nt * 16 + rl;
                part[((size_t)kz * MROWS + m) * 128 + br * 64 + n] = acc[mt][nt][j];
            }
        }
    }
}

// ---------------- reduce K-split partials -> xdbl fp32 + bf16 ----------------
__global__ __launch_bounds__(256)
void xreduce(const float* __restrict__ part, float* __restrict__ xdbl,
             unsigned short* __restrict__ xdbl_bf)
{
    const size_t N = (size_t)MROWS * 128;
    size_t i = ((size_t)blockIdx.x * 256 + threadIdx.x) * 4;
    float4 s = *(const float4*)(part + i);
#pragma unroll
    for (int kz = 1; kz < KS; kz++) {
        float4 p = *(const float4*)(part + kz * N + i);
        s.x += p.x; s.y += p.y; s.z += p.z; s.w += p.w;
    }
    *(float4*)(xdbl + i) = s;
    ushort4 o;
    o.x = f2bf(s.x); o.y = f2bf(s.y); o.z = f2bf(s.z); o.w = f2bf(s.w);
    *(ushort4*)(xdbl_bf + i) = o;
}

// ---------------- dt MFMA: dt[m,n] = softplus(sum_{k<32} xdbl_bf[m,boff+k]*w[n,k] + bias[n]) ----------------
// grid (DI/128, MROWS/128, 2). Single K-step (K=32). bf16 out.
__global__ __launch_bounds__(256)
void dt_mfma(const unsigned short* __restrict__ xdbl_bf,
             const unsigned short* __restrict__ wf, const unsigned short* __restrict__ wb,
             const float* __restrict__ biasf, const float* __restrict__ biasb,
             unsigned short* __restrict__ dtf, unsigned short* __restrict__ dtb)
{
    const int br = blockIdx.z;
    const unsigned short* B = br ? wb : wf;
    const float* bias = br ? biasb : biasf;
    unsigned short* C = br ? dtb : dtf;
    const size_t bn = (size_t)blockIdx.x * 128;
    const size_t bm = (size_t)blockIdx.y * 128;

    __shared__ unsigned short sA[128 * 32];
    __shared__ unsigned short sB[128 * 32];
    const int tid = threadIdx.x;
    const int lane = tid & 63;
    const int w = tid >> 6;
    const int wr = w >> 1, wc = w & 1;
    const int r4 = lane >> 2;
    const int c8 = (lane & 3) * 8;
    const int rl = lane & 15;
    const int kq = (lane >> 4) * 8;

#pragma unroll
    for (int i = 0; i < 2; i++) {
        int row = i * 64 + w * 16 + r4;
        const unsigned short* ga = xdbl_bf + (bm + row) * (size_t)128 + br * 64 + c8;
        char* la = (char*)sA + i * 4096 + w * 1024;
        __builtin_amdgcn_global_load_lds((const __attribute__((address_space(1))) void*)ga,
                                         (__attribute__((address_space(3))) void*)la, 16, 0, 0);
        const unsigned short* gb = B + (bn + row) * (size_t)DTR + c8;
        char* lb = (char*)sB + i * 4096 + w * 1024;
        __builtin_amdgcn_global_load_lds((const __attribute__((address_space(1))) void*)gb,
                                         (__attribute__((address_space(3))) void*)lb, 16, 0, 0);
    }
    __syncthreads();

    bf16x8 af[4], bfr[4];
#pragma unroll
    for (int t = 0; t < 4; t++) {
        af[t]  = *(const bf16x8*)&sA[(wr * 64 + t * 16 + rl) * 32 + kq];
        bfr[t] = *(const bf16x8*)&sB[(wc * 64 + t * 16 + rl) * 32 + kq];
    }
    f32x4 acc[4][4];
#pragma unroll
    for (int i = 0; i < 4; i++)
#pragma unroll
        for (int j = 0; j < 4; j++) acc[i][j] = (f32x4){0.f, 0.f, 0.f, 0.f};
#pragma unroll
    for (int mt = 0; mt < 4; mt++)
#pragma unroll
        for (int nt = 0; nt < 4; nt++)
            acc[mt][nt] = __builtin_amdgcn_mfma_f32_16x16x32_bf16(af[mt], bfr[nt], acc[mt][nt], 0, 0, 0);

    const int rq = lane >> 4;
#pragma unroll
    for (int nt = 0; nt < 4; nt++) {
        size_t n = bn + wc * 64 + nt * 16 + rl;
        float bv = bias[n];
#pragma unroll
        for (int mt = 0; mt < 4; mt++) {
#pragma unroll
            for (int j = 0; j < 4; j++) {
                size_t m = bm + wr * 64 + mt * 16 + rq * 4 + j;
                C[m * (size_t)DI + n] = f2bf(softplusf(acc[mt][nt][j] + bv));
            }
        }
    }
}

// ---------------- Depthwise causal (fwd) + anti-causal (bwd) conv + SiLU (bf16 io) ----------------
__global__ __launch_bounds__(256)
void conv_kernel(const unsigned short* __restrict__ xz,
                 const float* __restrict__ cwf, const float* __restrict__ cbf,
                 const float* __restrict__ cwb, const float* __restrict__ cbb,
                 unsigned short* __restrict__ xcf, unsigned short* __restrict__ xcb)
{
    int r = blockIdx.x;           // 0..8191
    int b = r >> 11, l = r & (L_SEQ - 1);
    int tid = threadIdx.x;
#pragma unroll
    for (int i = 0; i < 4; i++) {
        int d = tid + (i << 8);
        float accf = cbf[d], accb = cbb[d];
#pragma unroll
        for (int k = 0; k < 4; k++) {
            int lf = l - 3 + k;
            if (lf >= 0)
                accf += bf2f(xz[((size_t)(b * L_SEQ + lf)) * (2 * DI) + d]) * cwf[(d << 2) + k];
            int lb = l + k;
            if (lb < L_SEQ)
                accb += bf2f(xz[((size_t)(b * L_SEQ + lb)) * (2 * DI) + d]) * cwb[(d << 2) + 3 - k];
        }
        xcf[(size_t)r * DI + d] = f2bf(siluf(accf));
        xcb[(size_t)r * DI + d] = f2bf(siluf(accb));
    }
}

// ---------------- Chunked selective scan ----------------
__global__ __launch_bounds__(256)
void scan_pass1(const unsigned short* __restrict__ xcf, const unsigned short* __restrict__ xcb,
                const unsigned short* __restrict__ dtf, const unsigned short* __restrict__ dtb,
                const float* __restrict__ xdbl,
                const float* __restrict__ alf, const float* __restrict__ alb,
                float* __restrict__ q_buf, float* __restrict__ dtsum_buf)
{
    const int bid = blockIdx.x;
    const int d  = ((bid & 3) << 8) + threadIdx.x;
    const int c  = (bid >> 2) & 31;
    const int b  = (bid >> 7) & 3;
    const int br = bid >> 9;

    const unsigned short* xc_buf = br ? xcb : xcf;
    const unsigned short* dt_buf = br ? dtb : dtf;
    const float* Alog = br ? alb : alf;
    const int boff = br * 64;

    float a[16];
#pragma unroll
    for (int s = 0; s < 16; s++) a[s] = -__expf(Alog[d * DS + s]);

    float h[16];
#pragma unroll
    for (int s = 0; s < 16; s++) h[s] = 0.f;
    float Dt = 0.f;

    const size_t rowbase = (size_t)b * L_SEQ;
    const int lstart = br ? (L_SEQ - 1 - c * LC) : (c * LC);
    const int dl = br ? -1 : 1;

    size_t r0 = rowbase + lstart;
    float dt = bf2f(dt_buf[r0 * DI + d]);
    float xc = bf2f(xc_buf[r0 * DI + d]);

    for (int i = 0; i < LC; i++) {
        size_t r = rowbase + lstart + i * dl;
        float dt_n = 0.f, xc_n = 0.f;
        if (i < LC - 1) {
            size_t rn = rowbase + lstart + (i + 1) * dl;
            dt_n = bf2f(dt_buf[rn * DI + d]);
            xc_n = bf2f(xc_buf[rn * DI + d]);
        }
        const float* brow = xdbl + r * 128 + boff + 32;  // wave-uniform
        float w = dt * xc;
        Dt += dt;
#pragma unroll
        for (int s = 0; s < 16; s++) {
            float e = __expf(dt * a[s]);
            h[s] = e * h[s] + w * brow[s];
        }
        dt = dt_n; xc = xc_n;
    }

    size_t base = ((((size_t)br * 4 + b) * NCH + c) * DI + d);
#pragma unroll
    for (int s = 0; s < 16; s++) q_buf[base * 16 + s] = h[s];
    dtsum_buf[base] = Dt;
}

__global__ __launch_bounds__(256)
void scan_pass2(const float* __restrict__ q_buf, const float* __restrict__ dtsum_buf,
                const float* __restrict__ alf, const float* __restrict__ alb,
                float* __restrict__ h_start)
{
    int idx = blockIdx.x * 16 + (threadIdx.x >> 4);  // channel 0..8191
    int s = threadIdx.x & 15;
    int br = idx >> 12;
    int b  = (idx >> 10) & 3;
    int d  = idx & 1023;
    const float* Alog = br ? alb : alf;
    float a = -__expf(Alog[d * DS + s]);
    float h = 0.f;
    for (int c = 0; c < NCH; c++) {
        size_t base = ((((size_t)br * 4 + b) * NCH + c) * DI + d);
        h_start[base * 16 + s] = h;
        float Dt = dtsum_buf[base];
        float qv = q_buf[base * 16 + s];
        h = __expf(a * Dt) * h + qv;
    }
}

__global__ __launch_bounds__(256)
void scan_pass3(const unsigned short* __restrict__ xz,
                const unsigned short* __restrict__ xcf, const unsigned short* __restrict__ xcb,
                const unsigned short* __restrict__ dtf, const unsigned short* __restrict__ dtb,
                const float* __restrict__ xdbl,
                const float* __restrict__ alf, const float* __restrict__ alb,
                const float* __restrict__ dsf, const float* __restrict__ dsb,
                const float* __restrict__ h_start,
                unsigned short* __restrict__ yf, unsigned short* __restrict__ yb)
{
    const int bid = blockIdx.x;
    const int d  = ((bid & 3) << 8) + threadIdx.x;
    const int c  = (bid >> 2) & 31;
    const int b  = (bid >> 7) & 3;
    const int br = bid >> 9;

    const unsigned short* xc_buf = br ? xcb : xcf;
    const unsigned short* dt_buf = br ? dtb : dtf;
    const float* Alog = br ? alb : alf;
    const float* Dp   = br ? dsb : dsf;
    const int boff = br * 64;

    float a[16];
#pragma unroll
    for (int s = 0; s < 16; s++) a[s] = -__expf(Alog[d * DS + s]);
    float Dv = Dp[d];

    size_t base = ((((size_t)br * 4 + b) * NCH + c) * DI + d);
    float h[16];
#pragma unroll
    for (int s = 0; s < 16; s++) h[s] = h_start[base * 16 + s];

    unsigned short* yst = br ? yb : yf;

    const size_t rowbase = (size_t)b * L_SEQ;
    const int lstart = br ? (L_SEQ - 1 - c * LC) : (c * LC);
    const int dl = br ? -1 : 1;

    size_t r0 = rowbase + lstart;
    float dt = bf2f(dt_buf[r0 * DI + d]);
    float xc = bf2f(xc_buf[r0 * DI + d]);
    float zv = bf2f(xz[r0 * (2 * DI) + DI + d]);

    for (int i = 0; i < LC; i++) {
        size_t r = rowbase + lstart + i * dl;
        float dt_n = 0.f, xc_n = 0.f, zv_n = 0.f;
        if (i < LC - 1) {
            size_t rn = rowbase + lstart + (i + 1) * dl;
            dt_n = bf2f(dt_buf[rn * DI + d]);
            xc_n = bf2f(xc_buf[rn * DI + d]);
            zv_n = bf2f(xz[rn * (2 * DI) + DI + d]);
        }
        const float* brow = xdbl + r * 128 + boff + 32;  // wave-uniform
        const float* crow = brow + 16;                   // wave-uniform
        float w = dt * xc;
        float p0 = 0.f, p1 = 0.f;
#pragma unroll
        for (int s = 0; s < 16; s += 2) {
            float e0 = __expf(dt * a[s]);
            h[s] = e0 * h[s] + w * brow[s];
            p0 += h[s] * crow[s];
            float e1 = __expf(dt * a[s + 1]);
            h[s + 1] = e1 * h[s + 1] + w * brow[s + 1];
            p1 += h[s + 1] * crow[s + 1];
        }
        float y = (p0 + p1 + xc * Dv) * siluf(zv);
        yst[r * (size_t)DI + d] = f2bf(y);
        dt = dt_n; xc = xc_n; zv = zv_n;
    }
}

extern "C" void kernel_launch(void* const* d_in, const int* in_sizes, int n_in,
                              void* d_out, int out_size, void* d_ws, size_t ws_size,
                              hipStream_t stream)
{
    const float* hs   = (const float*)d_in[0];
    const float* nw   = (const float*)d_in[1];
    const float* nbp  = (const float*)d_in[2];
    const float* ipw  = (const float*)d_in[3];
    const float* opw  = (const float*)d_in[4];
    const float* cwf  = (const float*)d_in[5];
    const float* cbf  = (const float*)d_in[6];
    const float* xpwf = (const float*)d_in[7];
    const float* dtwf = (const float*)d_in[8];
    const float* dtbf = (const float*)d_in[9];
    const float* alf  = (const float*)d_in[10];
    const float* dsf  = (const float*)d_in[11];
    const float* cwb  = (const float*)d_in[12];
    const float* cbb  = (const float*)d_in[13];
    const float* xpwb = (const float*)d_in[14];
    const float* dtwb = (const float*)d_in[15];
    const float* dtbb = (const float*)d_in[16];
    const float* alb  = (const float*)d_in[17];
    const float* dsb  = (const float*)d_in[18];

    float* out   = (float*)d_out;                       // [8192][512]
    float* resid = out + (size_t)MROWS * DM;            // [8192][512]

    // ws layout (~165 MiB)
    char* p = (char*)d_ws;
    unsigned short* h_bf  = (unsigned short*)p; p += (size_t)MROWS * DM * 2;        // 8 MB
    unsigned short* xz_bf = (unsigned short*)p; p += (size_t)MROWS * 2 * DI * 2;    // 32 MB
    unsigned short* xcf_bf = (unsigned short*)p; p += (size_t)MROWS * DI * 2;       // 16 MB
    unsigned short* xcb_bf = (unsigned short*)p; p += (size_t)MROWS * DI * 2;
    unsigned short* dtf_bf = (unsigned short*)p; p += (size_t)MROWS * DI * 2;
    unsigned short* dtb_bf = (unsigned short*)p; p += (size_t)MROWS * DI * 2;
    unsigned short* yf_bf  = (unsigned short*)p; p += (size_t)MROWS * DI * 2;
    unsigned short* yb_bf  = (unsigned short*)p; p += (size_t)MROWS * DI * 2;
    float* xpart  = (float*)p; p += (size_t)KS * MROWS * 128 * 4;                   // 16 MB
    float* xdbl   = (float*)p; p += (size_t)MROWS * 128 * 4;                        // 4 MB
    unsigned short* xdbl_bf = (unsigned short*)p; p += (size_t)MROWS * 128 * 2;     // 2 MB
    float* q_buf  = (float*)p; p += (size_t)2 * NB * NCH * DI * 16 * 4;             // 16 MB
    float* dtsum  = (float*)p; p += (size_t)2 * NB * NCH * DI * 4;                  // 1 MB
    unsigned short* ipw_bf  = (unsigned short*)p; p += (size_t)2 * DI * DM * 2;     // 2 MB
    unsigned short* opw_bf  = (unsigned short*)p; p += (size_t)DM * DI * 2;         // 1 MB
    unsigned short* xpwf_bf = (unsigned short*)p; p += (size_t)64 * DI * 2;
    unsigned short* xpwb_bf = (unsigned short*)p; p += (size_t)64 * DI * 2;
    unsigned short* dtwf_bf = (unsigned short*)p; p += (size_t)DI * DTR * 2;
    unsigned short* dtwb_bf = (unsigned short*)p; p += (size_t)DI * DTR * 2;
    float* h_st = out;  // d_out front half as mid-pipeline scratch; overwritten by final gemm

    // weight casts
    cast_bf16<<<(2 * DI * DM) / 1024, 256, 0, stream>>>(ipw, ipw_bf, 2 * DI * DM);
    cast_bf16<<<(DM * DI) / 1024, 256, 0, stream>>>(opw, opw_bf, DM * DI);
    cast_bf16<<<(64 * DI) / 1024, 256, 0, stream>>>(xpwf, xpwf_bf, 64 * DI);
    cast_bf16<<<(64 * DI) / 1024, 256, 0, stream>>>(xpwb, xpwb_bf, 64 * DI);
    cast_bf16<<<(DI * DTR) / 1024, 256, 0, stream>>>(dtwf, dtwf_bf, DI * DTR);
    cast_bf16<<<(DI * DTR) / 1024, 256, 0, stream>>>(dtwb, dtwb_bf, DI * DTR);

    ln_kernel<<<MROWS, 256, 0, stream>>>(hs, nw, nbp, h_bf, resid);

    // xz = h @ in_proj_w^T   (M=8192, N=2048, K=512), bf16 out
    gemm_bf16mm<0, 1><<<dim3((2 * DI) / 128, MROWS / 128), 256, 0, stream>>>(
        h_bf, nullptr, DM, ipw_bf, DM, xz_bf, 2 * DI, DM, 1.f);

    conv_kernel<<<MROWS, 256, 0, stream>>>(xz_bf, cwf, cbf, cwb, cbb, xcf_bf, xcb_bf);

    // x_dbl: K-split MFMA + reduce
    xproj_mfma<<<dim3(KS, MROWS / 128, 2), 256, 0, stream>>>(
        xcf_bf, xcb_bf, xpwf_bf, xpwb_bf, xpart);
    xreduce<<<(MROWS * 128) / 1024, 256, 0, stream>>>(xpart, xdbl, xdbl_bf);

    // dt = softplus(x_dbl[:, :32] @ dt_proj_w^T + b), bf16 out
    dt_mfma<<<dim3(DI / 128, MROWS / 128, 2), 256, 0, stream>>>(
        xdbl_bf, dtwf_bf, dtwb_bf, dtbf, dtbb, dtf_bf, dtb_bf);

    // chunked selective scan
    scan_pass1<<<2 * NB * NCH * (DI / 256), 256, 0, stream>>>(
        xcf_bf, xcb_bf, dtf_bf, dtb_bf, xdbl, alf, alb, q_buf, dtsum);
    scan_pass2<<<(2 * NB * DI) / 16, 256, 0, stream>>>(
        q_buf, dtsum, alf, alb, h_st);
    scan_pass3<<<2 * NB * NCH * (DI / 256), 256, 0, stream>>>(
        xz_bf, xcf_bf, xcb_bf, dtf_bf, dtb_bf, xdbl, alf, alb, dsf, dsb, h_st, yf_bf, yb_bf);

    // out = (y_f + y_b) @ out_proj_w^T * 0.5  (M=8192, N=512, K=1024), DUAL reg-staged A
    gemm_bf16mm<1, 0><<<dim3(DM / 128, MROWS / 128), 256, 0, stream>>>(
        yf_bf, yb_bf, DI, opw_bf, DI, out, DM, DI, 0.5f);
}